// Round 10
// baseline (867.939 us; speedup 1.0000x reference)
//
#include <hip/hip_runtime.h>

// LSTMAutoRegressive: B=1024, T=1024, H1=64, H2=32, n_in=n_out=1.
// v9 = v5 base + instruction diet. Measured law (R5-R8): step time =
// MFMA-busy + VALU-busy per SIMD (no overlap, any phasing) -> minimize
// total issue cycles. Single-acc MFMA chains (no merge adds), bias2 via
// VALU, float2 x/d window, joint-rcp actf, 1 lgkm-barrier/step.
// 64 wgs x 512 threads. Role-split: w0-3 L1 (4 tiles), w4-7 L2 (2 tiles)+y.

using short8 = __attribute__((ext_vector_type(8))) short;
using f32x4  = __attribute__((ext_vector_type(4))) float;
typedef unsigned short us;
typedef unsigned int   uu;

#define MFMA16(A,B,C) __builtin_amdgcn_mfma_f32_16x16x32_bf16((A),(B),(C),0,0,0)
#define BARRIER() asm volatile("s_waitcnt lgkmcnt(0)\n\ts_barrier" ::: "memory")

constexpr int   T     = 1024;
constexpr float LOG2E = 1.44269504088896f;

__device__ __forceinline__ us    bhi(float f){ return (us)(__float_as_uint(f) >> 16); }
__device__ __forceinline__ float hmask(float f){ return __uint_as_float(__float_as_uint(f) & 0xFFFF0000u); }
// k-pos -> unit permutations (match packed h write layouts)
__device__ __forceinline__ int upos1(int p){ return 16*(p>>4) + 4*(p&3) + ((p>>2)&3); }
__device__ __forceinline__ int upos2(int p){ return 8*(p>>3) + 4*(p&1) + ((p&7)>>1); }

__device__ __forceinline__ float rcpf(float x){ return __builtin_amdgcn_rcpf(x); }
#if __has_builtin(__builtin_amdgcn_exp2f)
__device__ __forceinline__ float ex2(float x){ return __builtin_amdgcn_exp2f(x); }
#else
__device__ __forceinline__ float ex2(float x){
    float r; asm("v_exp_f32 %0, %1\n\ts_nop 0" : "=v"(r) : "v"(x)); return r;
}
#endif

// gates pre-scaled: i,f,o by -log2e ; g by +2log2e. cs = 2log2e*c carried.
// Joint reciprocal: 1 rcp for 4 gates + 1 for tanh(c): 5 exp + 2 rcp.
__device__ __forceinline__ float actf(const f32x4 a, float& cs){
    f32x4 E;
    E[0] = ex2(a[0]); E[1] = ex2(a[1]); E[2] = ex2(a[2]); E[3] = ex2(a[3]);
    f32x4 p = E + 1.0f;                       // vectorized (pk_add candidate)
    float pif = p[0] * p[1], pgo = p[2] * p[3];
    float r   = rcpf(pif * pgo);
    float rif = r * pgo, rgo = r * pif;
    float si = rif * p[1], sf = rif * p[0];
    float rg = rgo * p[3], so = rgo * p[2];
    float gt2 = __builtin_fmaf(-4.0f * LOG2E, rg, 2.0f * LOG2E);   // 2log2e*tanh(g)
    cs = __builtin_fmaf(sf, cs, si * gt2);
    float Ec = ex2(cs);
    float tc = __builtin_fmaf(-2.0f, rcpf(1.0f + Ec), 1.0f);       // tanh(c)
    return so * tc;
}

__global__ __launch_bounds__(512, 2)
void lstm_ar_kernel(const float* __restrict__ x_in,
                    const float* __restrict__ dly_in,
                    const float* __restrict__ W_ih1, const float* __restrict__ W_hh1,
                    const float* __restrict__ b_ih1, const float* __restrict__ b_hh1,
                    const float* __restrict__ W_ih2, const float* __restrict__ W_hh2,
                    const float* __restrict__ b_ih2, const float* __restrict__ b_hh2,
                    const float* __restrict__ W_out, const float* __restrict__ b_out,
                    float* __restrict__ out)
{
    // h1 rows: upos1 order [hi 0..63 | lo 64..127], stride 136 us (272B).
    // h2 rows: upos2 order [hi 0..31 | lo 32..63],  stride 72 us (144B).
    __shared__ __align__(16) us H1[2][16][136];
    __shared__ __align__(16) us H2[2][16][72];

    const int tid = threadIdx.x, w = tid >> 6, l = tid & 63;
    const int lb = l & 15, lq = l >> 4;
    const int bglob = blockIdx.x * 16 + lb;

    for (int i = tid; i < 2*16*136; i += 512) ((us*)H1)[i] = 0;
    for (int i = tid; i < 2*16*72;  i += 512) ((us*)H2)[i] = 0;

    const int ty = lb & 3, du = lb >> 2;
    const float srow = (ty == 2) ? 2.0f * LOG2E : -LOG2E;
    const bool isA = (w < 4);
    const int  w2  = w & 3;

    // A role: 4 L1 tiles. B role: 2 L2 tiles (+ y on w4).
    short8 w1h[4][2], w1l[4][2], wxd[4];
    short8 w2h[2][2], w2l[2][2], whh[2], whl[2];
    f32x4  bias2v[2] = {{0,0,0,0},{0,0,0,0}};
    short8 wyh = {}, wyl = {};

    if (isA) {
        #pragma unroll
        for (int m = 0; m < 4; ++m) {
            const int G = ty * 64 + 16 * w + 4 * m + du;
            #pragma unroll
            for (int s = 0; s < 2; ++s)
                #pragma unroll
                for (int i = 0; i < 8; ++i) {
                    int p = 32*s + 8*lq + i;
                    float v = srow * W_hh1[G * 64 + upos1(p)];
                    float vh = hmask(v);
                    w1h[m][s][i] = (short)bhi(v);
                    w1l[m][s][i] = (short)bhi(v - vh);
                }
            float q4 = 0.25f * srow;
            float wx = q4 * W_ih1[G*2+0], wd = q4 * W_ih1[G*2+1];
            float bb = q4 * (b_ih1[G] + b_hh1[G]);
            float wxh = hmask(wx), wdh = hmask(wd), bbh = hmask(bb);
            wxd[m] = (short8){ (short)bhi(wx), (short)bhi(wx), (short)bhi(wd),
                               (short)bhi(wd), (short)bhi(bb), (short)bhi(wx - wxh),
                               (short)bhi(wd - wdh), (short)bhi(bb - bbh) };
        }
    } else {
        #pragma unroll
        for (int j = 0; j < 2; ++j) {
            const int G2 = ty * 32 + 8 * w2 + 4 * j + du;
            #pragma unroll
            for (int s = 0; s < 2; ++s)
                #pragma unroll
                for (int i = 0; i < 8; ++i) {
                    int p = 32*s + 8*lq + i;
                    float v = srow * W_ih2[G2 * 64 + upos1(p)];   // h1 pos-order
                    float vh = hmask(v);
                    w2h[j][s][i] = (short)bhi(v);
                    w2l[j][s][i] = (short)bhi(v - vh);
                }
            #pragma unroll
            for (int i = 0; i < 8; ++i) {
                float v = srow * W_hh2[G2 * 32 + upos2(8*lq + i)]; // h2 pos-order
                float vh = hmask(v);
                whh[j][i] = (short)bhi(v);
                whl[j][i] = (short)bhi(v - vh);
            }
            // bias as VALU add in ACT view: lane (lb,lq) reg r = gate r of
            // unit u2 = 8w2 + 4j + lq  (scale per gate type r)
            #pragma unroll
            for (int r = 0; r < 4; ++r) {
                const float sr = (r == 2) ? 2.0f * LOG2E : -LOG2E;
                const int Gb = r * 32 + 8 * w2 + 4 * j + lq;
                bias2v[j][r] = sr * (b_ih2[Gb] + b_hh2[Gb]);
            }
        }
        if (w == 4) {
            #pragma unroll
            for (int i = 0; i < 8; ++i) {
                float v = (lb == 0) ? W_out[upos2(8*lq + i)] : 0.0f;
                float vh = hmask(v);
                wyh[i] = (short)bhi(v);
                wyl[i] = (short)bhi(v - vh);
            }
        }
    }
    const float bout = b_out[0];
    const f32x4 Z4 = {0.f,0.f,0.f,0.f};

    const float* xp = x_in   + bglob * T;
    const float* dp = dly_in + bglob * T;
    float*       op = out    + bglob * T;

    float c1[4] = {0.f,0.f,0.f,0.f};   // A: 4 units; B: [0..1] = c2
    float2 xc = {0,0}, dc = {0,0};
    if (isA) { xc = *(const float2*)xp; dc = *(const float2*)dp; }

    __syncthreads();

    auto STEP = [&](const int t, const int pw, const int pr,
                    const float xv, const float dv) {
        if (isA) {
            if (t < T) {
                const us* r1 = &H1[pr][lb][0];
                short8 hh0 = *(const short8*)(r1 + 8*lq);
                short8 hh1 = *(const short8*)(r1 + 32 + 8*lq);
                short8 hl0 = *(const short8*)(r1 + 64 + 8*lq);
                short8 hl1 = *(const short8*)(r1 + 96 + 8*lq);
                uu xu = __float_as_uint(xv), duu = __float_as_uint(dv);
                float xlo = xv - __uint_as_float(xu & 0xFFFF0000u);
                float dlo = dv - __uint_as_float(duu & 0xFFFF0000u);
                short8 bx;
                ((uu*)&bx)[0] = (xu >> 16)  | (__float_as_uint(xlo) & 0xFFFF0000u);
                ((uu*)&bx)[1] = (duu >> 16) | (__float_as_uint(dlo) & 0xFFFF0000u);
                ((uu*)&bx)[2] = 0x00003F80u | (xu & 0xFFFF0000u);
                ((uu*)&bx)[3] = (duu >> 16) | 0x3F800000u;

                // single 7-chain per tile, 4 tiles interleaved (dep gap 64cy)
                f32x4 a[4];
                #pragma unroll
                for (int m = 0; m < 4; ++m) a[m] = MFMA16(w1h[m][0], hh0, Z4);
                #pragma unroll
                for (int m = 0; m < 4; ++m) a[m] = MFMA16(w1h[m][0], hl0, a[m]);
                #pragma unroll
                for (int m = 0; m < 4; ++m) a[m] = MFMA16(w1l[m][0], hh0, a[m]);
                #pragma unroll
                for (int m = 0; m < 4; ++m) a[m] = MFMA16(wxd[m],    bx,  a[m]);
                #pragma unroll
                for (int m = 0; m < 4; ++m) a[m] = MFMA16(w1h[m][1], hh1, a[m]);
                #pragma unroll
                for (int m = 0; m < 4; ++m) a[m] = MFMA16(w1h[m][1], hl1, a[m]);
                #pragma unroll
                for (int m = 0; m < 4; ++m) a[m] = MFMA16(w1l[m][1], hh1, a[m]);

                float hv[4];
                #pragma unroll
                for (int m = 0; m < 4; ++m) hv[m] = actf(a[m], c1[m]);

                uu P0 = (__float_as_uint(hv[0]) >> 16) | (__float_as_uint(hv[1]) & 0xFFFF0000u);
                uu P1 = (__float_as_uint(hv[2]) >> 16) | (__float_as_uint(hv[3]) & 0xFFFF0000u);
                float e0 = hv[0]-hmask(hv[0]), e1 = hv[1]-hmask(hv[1]);
                float e2 = hv[2]-hmask(hv[2]), e3 = hv[3]-hmask(hv[3]);
                uu Q0 = (__float_as_uint(e0) >> 16) | (__float_as_uint(e1) & 0xFFFF0000u);
                uu Q1 = (__float_as_uint(e2) >> 16) | (__float_as_uint(e3) & 0xFFFF0000u);
                *(uint2*)&H1[pw][lb][16*w + 4*lq]      = (uint2){P0, P1};
                *(uint2*)&H1[pw][lb][64 + 16*w + 4*lq] = (uint2){Q0, Q1};
            }
        } else {
            short8 g0 = {}, g1 = {};
            if (t >= 1) {
                const us* r2 = &H2[pw][lb][0];       // h2(t-2): hi, lo
                g0 = *(const short8*)(r2 + 8*lq);
                g1 = *(const short8*)(r2 + 32 + 8*lq);
            }
            // y(t-2) on wave 4
            if (w == 4 && t >= 2) {
                f32x4 yA = MFMA16(wyh, g0, Z4);
                f32x4 yB = MFMA16(wyh, g1, Z4);
                yA = MFMA16(wyl, g0, yA);
                if (lq == 0) op[t-2] = yA[0] + yB[0] + bout;
            }
            // L2: h2(t-1) from h1(t-1) [slot pr] and h2(t-2) [slot pw]
            if (t >= 1 && t <= T) {
                const us* r1 = &H1[pr][lb][0];
                short8 hh0 = *(const short8*)(r1 + 8*lq);
                short8 hh1 = *(const short8*)(r1 + 32 + 8*lq);
                short8 hl0 = *(const short8*)(r1 + 64 + 8*lq);
                short8 hl1 = *(const short8*)(r1 + 96 + 8*lq);

                // per tile: ih-chain (6) + hh-chain (3); 4 chains interleaved
                f32x4 q[2], h[2];
                #pragma unroll
                for (int j = 0; j < 2; ++j) { q[j] = MFMA16(w2h[j][0], hh0, Z4);
                                              h[j] = MFMA16(whh[j],    g0,  Z4); }
                #pragma unroll
                for (int j = 0; j < 2; ++j) { q[j] = MFMA16(w2h[j][0], hl0, q[j]);
                                              h[j] = MFMA16(whh[j],    g1,  h[j]); }
                #pragma unroll
                for (int j = 0; j < 2; ++j) { q[j] = MFMA16(w2l[j][0], hh0, q[j]);
                                              h[j] = MFMA16(whl[j],    g0,  h[j]); }
                #pragma unroll
                for (int j = 0; j < 2; ++j)   q[j] = MFMA16(w2h[j][1], hh1, q[j]);
                #pragma unroll
                for (int j = 0; j < 2; ++j)   q[j] = MFMA16(w2h[j][1], hl1, q[j]);
                #pragma unroll
                for (int j = 0; j < 2; ++j)   q[j] = MFMA16(w2l[j][1], hh1, q[j]);

                float h2v[2];
                #pragma unroll
                for (int j = 0; j < 2; ++j) {
                    f32x4 g = (q[j] + h[j]) + bias2v[j];   // vector adds
                    h2v[j] = actf(g, c1[j]);
                }
                uu ph = (__float_as_uint(h2v[0]) >> 16) | (__float_as_uint(h2v[1]) & 0xFFFF0000u);
                float e0 = h2v[0]-hmask(h2v[0]), e1 = h2v[1]-hmask(h2v[1]);
                uu pl = (__float_as_uint(e0) >> 16) | (__float_as_uint(e1) & 0xFFFF0000u);
                *(uu*)&H2[pr][lb][8*w2 + 2*lq]      = ph;
                *(uu*)&H2[pr][lb][32 + 8*w2 + 2*lq] = pl;
            }
        }
        BARRIER();
    };

    #pragma unroll 1
    for (int tt = 0; tt <= 512; ++tt) {
        float2 xn = xc, dn = dc;
        if (isA) {
            const int wn = (tt < 511) ? tt + 1 : 511;
            xn = *(const float2*)(xp + 2*wn);
            dn = *(const float2*)(dp + 2*wn);
        }
        STEP(2*tt,     0, 1, xc.x, dc.x);
        STEP(2*tt + 1, 1, 0, xc.y, dc.y);
        xc = xn; dc = dn;
    }
}

extern "C" void kernel_launch(void* const* d_in, const int* in_sizes, int n_in,
                              void* d_out, int out_size, void* d_ws, size_t ws_size,
                              hipStream_t stream) {
    lstm_ar_kernel<<<dim3(64), dim3(512), 0, stream>>>(
        (const float*)d_in[0],  (const float*)d_in[1],
        (const float*)d_in[2],  (const float*)d_in[3],
        (const float*)d_in[4],  (const float*)d_in[5],
        (const float*)d_in[6],  (const float*)d_in[7],
        (const float*)d_in[8],  (const float*)d_in[9],
        (const float*)d_in[10], (const float*)d_in[11],
        (float*)d_out);
}

// Round 11
// 706.651 us; speedup vs baseline: 1.2282x; 1.2282x over previous
//
#include <hip/hip_runtime.h>

// LSTMAutoRegressive: B=1024, T=1024, H1=64, H2=32, n_in=n_out=1.
// v10 = v5 base (best, 791us) + SINGLE change: h stored as one RTNE bf16
// (no h_lo corrections anywhere); W keeps bf16 hi/lo split. Kills 57/195
// MFMAs per wg-step (additive per-SIMD issue law measured R5-R9: time =
// MFMA-issue + VALU-issue; only total-cycle cuts help).
// 64 wgs x 512 threads. Role-split: w0-3 L1 (4 tiles), w4-7 L2 (2 tiles)+y.
// MFMA 16x16x32 bf16 swapped operands, gate-permuted A-rows, exp2-folded
// weights, xd folded as 7th MFMA k-step, 1 lgkm-only barrier per step.

using short8 = __attribute__((ext_vector_type(8))) short;
using f32x4  = __attribute__((ext_vector_type(4))) float;
typedef unsigned short us;
typedef unsigned int   uu;

#define MFMA16(A,B,C) __builtin_amdgcn_mfma_f32_16x16x32_bf16((A),(B),(C),0,0,0)
#define BARRIER() asm volatile("s_waitcnt lgkmcnt(0)\n\ts_barrier" ::: "memory")

constexpr int   T     = 1024;
constexpr float LOG2E = 1.44269504088896f;

__device__ __forceinline__ us    bhi(float f){ return (us)(__float_as_uint(f) >> 16); }
__device__ __forceinline__ float hmask(float f){ return __uint_as_float(__float_as_uint(f) & 0xFFFF0000u); }
// round-to-nearest-even bf16 bits
__device__ __forceinline__ uu rtne(float f){
    uu u = __float_as_uint(f);
    return (u + 0x7FFFu + ((u >> 16) & 1u)) >> 16;
}
// k-pos -> unit permutations (match packed h write layouts)
__device__ __forceinline__ int upos1(int p){ return 16*(p>>4) + 4*(p&3) + ((p>>2)&3); }
__device__ __forceinline__ int upos2(int p){ return 8*(p>>3) + 4*(p&1) + ((p&7)>>1); }

__device__ __forceinline__ float rcpf(float x){ return __builtin_amdgcn_rcpf(x); }
#if __has_builtin(__builtin_amdgcn_exp2f)
__device__ __forceinline__ float ex2(float x){ return __builtin_amdgcn_exp2f(x); }
#else
__device__ __forceinline__ float ex2(float x){
    float r; asm("v_exp_f32 %0, %1\n\ts_nop 0" : "=v"(r) : "v"(x)); return r;
}
#endif

// gates pre-scaled: i,f,o by -log2e ; g by +2log2e. cs = 2log2e*c carried.
// v5's original actf (4 gate rcp + tanh(c)): measured-cheapest variant.
__device__ __forceinline__ float actf(const f32x4 a, float& cs){
    float Ei = ex2(a[0]), Ef = ex2(a[1]), Eg = ex2(a[2]), Eo = ex2(a[3]);
    float si = rcpf(1.0f + Ei), sf = rcpf(1.0f + Ef);
    float rg = rcpf(1.0f + Eg), so = rcpf(1.0f + Eo);
    float gt2 = __builtin_fmaf(-4.0f * LOG2E, rg, 2.0f * LOG2E);   // 2log2e*tanh(g)
    cs = __builtin_fmaf(sf, cs, si * gt2);
    float Ec = ex2(cs);
    float tc = __builtin_fmaf(-2.0f, rcpf(1.0f + Ec), 1.0f);       // tanh(c)
    return so * tc;
}

__global__ __launch_bounds__(512, 2)
void lstm_ar_kernel(const float* __restrict__ x_in,
                    const float* __restrict__ dly_in,
                    const float* __restrict__ W_ih1, const float* __restrict__ W_hh1,
                    const float* __restrict__ b_ih1, const float* __restrict__ b_hh1,
                    const float* __restrict__ W_ih2, const float* __restrict__ W_hh2,
                    const float* __restrict__ b_ih2, const float* __restrict__ b_hh2,
                    const float* __restrict__ W_out, const float* __restrict__ b_out,
                    float* __restrict__ out)
{
    // h1 rows: upos1 order, 64 hi entries + pad, stride 72 us (144B).
    // h2 rows: upos2 order, 32 hi entries + pad, stride 40 us (80B).
    // (strides ≡ 4 words mod 32 banks -> 2-way b128 floor, conflict-free)
    __shared__ __align__(16) us H1[2][16][72];
    __shared__ __align__(16) us H2[2][16][40];

    const int tid = threadIdx.x, w = tid >> 6, l = tid & 63;
    const int lb = l & 15, lq = l >> 4;
    const int bglob = blockIdx.x * 16 + lb;

    for (int i = tid; i < 2*16*72; i += 512) ((us*)H1)[i] = 0;
    for (int i = tid; i < 2*16*40; i += 512) ((us*)H2)[i] = 0;

    const int ty = lb & 3, du = lb >> 2;
    const float srow = (ty == 2) ? 2.0f * LOG2E : -LOG2E;
    const bool isA = (w < 4);
    const int  w2  = w & 3;

    // A role: 4 L1 tiles. B role: 2 L2 tiles (+ y on w4).
    short8 w1h[4][2], w1l[4][2], wxd[4];
    short8 w2h[2][2], w2l[2][2], whh[2], whl[2], wbb[2];
    short8 wyh = {}, wyl = {};

    if (isA) {
        #pragma unroll
        for (int m = 0; m < 4; ++m) {
            const int G = ty * 64 + 16 * w + 4 * m + du;
            #pragma unroll
            for (int s = 0; s < 2; ++s)
                #pragma unroll
                for (int i = 0; i < 8; ++i) {
                    int p = 32*s + 8*lq + i;
                    float v = srow * W_hh1[G * 64 + upos1(p)];
                    float vh = hmask(v);
                    w1h[m][s][i] = (short)bhi(v);
                    w1l[m][s][i] = (short)bhi(v - vh);
                }
            float q4 = 0.25f * srow;
            float wx = q4 * W_ih1[G*2+0], wd = q4 * W_ih1[G*2+1];
            float bb = q4 * (b_ih1[G] + b_hh1[G]);
            float wxh = hmask(wx), wdh = hmask(wd), bbh = hmask(bb);
            wxd[m] = (short8){ (short)bhi(wx), (short)bhi(wx), (short)bhi(wd),
                               (short)bhi(wd), (short)bhi(bb), (short)bhi(wx - wxh),
                               (short)bhi(wd - wdh), (short)bhi(bb - bbh) };
        }
    } else {
        #pragma unroll
        for (int j = 0; j < 2; ++j) {
            const int G2 = ty * 32 + 8 * w2 + 4 * j + du;
            #pragma unroll
            for (int s = 0; s < 2; ++s)
                #pragma unroll
                for (int i = 0; i < 8; ++i) {
                    int p = 32*s + 8*lq + i;
                    float v = srow * W_ih2[G2 * 64 + upos1(p)];   // h1 pos-order
                    float vh = hmask(v);
                    w2h[j][s][i] = (short)bhi(v);
                    w2l[j][s][i] = (short)bhi(v - vh);
                }
            #pragma unroll
            for (int i = 0; i < 8; ++i) {
                float v = srow * W_hh2[G2 * 32 + upos2(8*lq + i)]; // h2 pos-order
                float vh = hmask(v);
                whh[j][i] = (short)bhi(v);
                whl[j][i] = (short)bhi(v - vh);
            }
            float bb = 0.25f * srow * (b_ih2[G2] + b_hh2[G2]);
            float bbh = hmask(bb);
            wbb[j] = (short8){ (short)bhi(bb), (short)bhi(bb - bbh), 0,0,0,0,0,0 };
        }
        if (w == 4) {
            #pragma unroll
            for (int i = 0; i < 8; ++i) {
                float v = (lb == 0) ? W_out[upos2(8*lq + i)] : 0.0f;
                float vh = hmask(v);
                wyh[i] = (short)bhi(v);
                wyl[i] = (short)bhi(v - vh);
            }
        }
    }
    const float bout = b_out[0];
    const short8 bB = (short8){(short)0x3F80,(short)0x3F80,0,0,0,0,0,0};
    const f32x4  Z4 = {0.f,0.f,0.f,0.f};

    const float* xp = x_in   + bglob * T;
    const float* dp = dly_in + bglob * T;
    float*       op = out    + bglob * T;

    float c1[4] = {0.f,0.f,0.f,0.f};   // A: 4 units; B: [0..1] = c2
    float2 xc = {0,0}, dc = {0,0};
    if (isA) { xc = *(const float2*)xp; dc = *(const float2*)dp; }

    __syncthreads();

    auto STEP = [&](const int t, const int pw, const int pr,
                    const float xv, const float dv) {
        if (isA) {
            if (t < T) {
                const us* r1 = &H1[pr][lb][0];
                short8 hh0 = *(const short8*)(r1 + 8*lq);
                short8 hh1 = *(const short8*)(r1 + 32 + 8*lq);
                uu xu = __float_as_uint(xv), duu = __float_as_uint(dv);
                float xlo = xv - __uint_as_float(xu & 0xFFFF0000u);
                float dlo = dv - __uint_as_float(duu & 0xFFFF0000u);
                short8 bx;
                ((uu*)&bx)[0] = (xu >> 16)  | (__float_as_uint(xlo) & 0xFFFF0000u);
                ((uu*)&bx)[1] = (duu >> 16) | (__float_as_uint(dlo) & 0xFFFF0000u);
                ((uu*)&bx)[2] = 0x00003F80u | (xu & 0xFFFF0000u);
                ((uu*)&bx)[3] = (duu >> 16) | 0x3F800000u;

                // per tile: a0-chain (w_hi k0, w_lo k0, xd) + a1-chain (w_hi k1, w_lo k1)
                f32x4 a0[4], a1[4];
                #pragma unroll
                for (int m = 0; m < 4; ++m) a0[m] = MFMA16(w1h[m][0], hh0, Z4);
                #pragma unroll
                for (int m = 0; m < 4; ++m) a1[m] = MFMA16(w1h[m][1], hh1, Z4);
                #pragma unroll
                for (int m = 0; m < 4; ++m) a0[m] = MFMA16(w1l[m][0], hh0, a0[m]);
                #pragma unroll
                for (int m = 0; m < 4; ++m) a1[m] = MFMA16(w1l[m][1], hh1, a1[m]);
                #pragma unroll
                for (int m = 0; m < 4; ++m) a0[m] = MFMA16(wxd[m], bx, a0[m]);

                float hv[4];
                #pragma unroll
                for (int m = 0; m < 4; ++m) {
                    f32x4 g = { a0[m][0]+a1[m][0], a0[m][1]+a1[m][1],
                                a0[m][2]+a1[m][2], a0[m][3]+a1[m][3] };
                    hv[m] = actf(g, c1[m]);
                }
                uu P0 = rtne(hv[0]) | (rtne(hv[1]) << 16);
                uu P1 = rtne(hv[2]) | (rtne(hv[3]) << 16);
                *(uint2*)&H1[pw][lb][16*w + 4*lq] = (uint2){P0, P1};
            }
        } else {
            short8 g0 = {};
            if (t >= 1) {
                const us* r2 = &H2[pw][lb][0];       // h2(t-2)
                g0 = *(const short8*)(r2 + 8*lq);
            }
            // y(t-2) on wave 4
            if (w == 4 && t >= 2) {
                f32x4 yA = MFMA16(wyh, g0, Z4);
                f32x4 yB = MFMA16(wyl, g0, Z4);
                if (lq == 0) op[t-2] = yA[0] + yB[0] + bout;
            }
            // L2: h2(t-1) from h1(t-1) [slot pr] and h2(t-2) [slot pw]
            if (t >= 1 && t <= T) {
                const us* r1 = &H1[pr][lb][0];
                short8 hh0 = *(const short8*)(r1 + 8*lq);
                short8 hh1 = *(const short8*)(r1 + 32 + 8*lq);

                // per tile: qA (ih_hi k0, ih_lo k0, bias), qB (ih_hi k1, ih_lo k1),
                //           qC (hh_hi, hh_lo)
                f32x4 qA[2], qB[2], qC[2];
                #pragma unroll
                for (int j = 0; j < 2; ++j) {
                    qA[j] = MFMA16(w2h[j][0], hh0, Z4);
                    qB[j] = MFMA16(w2h[j][1], hh1, Z4);
                    qC[j] = MFMA16(whh[j],    g0,  Z4);
                }
                #pragma unroll
                for (int j = 0; j < 2; ++j) {
                    qA[j] = MFMA16(w2l[j][0], hh0, qA[j]);
                    qB[j] = MFMA16(w2l[j][1], hh1, qB[j]);
                    qC[j] = MFMA16(whl[j],    g0,  qC[j]);
                }
                #pragma unroll
                for (int j = 0; j < 2; ++j)
                    qA[j] = MFMA16(wbb[j], bB, qA[j]);

                float h2v[2];
                #pragma unroll
                for (int j = 0; j < 2; ++j) {
                    f32x4 g = { qA[j][0]+qB[j][0]+qC[j][0], qA[j][1]+qB[j][1]+qC[j][1],
                                qA[j][2]+qB[j][2]+qC[j][2], qA[j][3]+qB[j][3]+qC[j][3] };
                    h2v[j] = actf(g, c1[j]);
                }
                uu ph = rtne(h2v[0]) | (rtne(h2v[1]) << 16);
                *(uu*)&H2[pr][lb][8*w2 + 2*lq] = ph;
            }
        }
        BARRIER();
    };

    #pragma unroll 1
    for (int tt = 0; tt <= 512; ++tt) {
        float2 xn = xc, dn = dc;
        if (isA) {
            const int wn = (tt < 511) ? tt + 1 : 511;
            xn = *(const float2*)(xp + 2*wn);
            dn = *(const float2*)(dp + 2*wn);
        }
        STEP(2*tt,     0, 1, xc.x, dc.x);
        STEP(2*tt + 1, 1, 0, xc.y, dc.y);
        xc = xn; dc = dn;
    }
}

extern "C" void kernel_launch(void* const* d_in, const int* in_sizes, int n_in,
                              void* d_out, int out_size, void* d_ws, size_t ws_size,
                              hipStream_t stream) {
    lstm_ar_kernel<<<dim3(64), dim3(512), 0, stream>>>(
        (const float*)d_in[0],  (const float*)d_in[1],
        (const float*)d_in[2],  (const float*)d_in[3],
        (const float*)d_in[4],  (const float*)d_in[5],
        (const float*)d_in[6],  (const float*)d_in[7],
        (const float*)d_in[8],  (const float*)d_in[9],
        (const float*)d_in[10], (const float*)d_in[11],
        (float*)d_out);
}

// Round 12
// 640.455 us; speedup vs baseline: 1.3552x; 1.1034x over previous
//
#include <hip/hip_runtime.h>

// LSTMAutoRegressive: B=1024, T=1024, H1=64, H2=32, n_in=n_out=1.
// v11 = v10 + SINGLE change: weights as one RTNE bf16 (all w_lo MFMA chains
// dropped; h already RTNE bf16). MFMA/wg 138->82. Additive per-SIMD issue
// law (R5-R10): step = MFMA-issue + VALU-issue; this cuts the MFMA term.
// 64 wgs x 512 threads. Role-split: w0-3 L1 (4 tiles), w4-7 L2 (2 tiles)+y.
// MFMA 16x16x32 bf16 swapped operands, gate-permuted A-rows, exp2-folded
// weights, xd folded as 7th MFMA k-step, 1 lgkm-only barrier per step.

using short8 = __attribute__((ext_vector_type(8))) short;
using f32x4  = __attribute__((ext_vector_type(4))) float;
typedef unsigned short us;
typedef unsigned int   uu;

#define MFMA16(A,B,C) __builtin_amdgcn_mfma_f32_16x16x32_bf16((A),(B),(C),0,0,0)
#define BARRIER() asm volatile("s_waitcnt lgkmcnt(0)\n\ts_barrier" ::: "memory")

constexpr int   T     = 1024;
constexpr float LOG2E = 1.44269504088896f;

__device__ __forceinline__ us    bhi(float f){ return (us)(__float_as_uint(f) >> 16); }
__device__ __forceinline__ float hmask(float f){ return __uint_as_float(__float_as_uint(f) & 0xFFFF0000u); }
// round-to-nearest-even bf16 bits
__device__ __forceinline__ uu rtne(float f){
    uu u = __float_as_uint(f);
    return (u + 0x7FFFu + ((u >> 16) & 1u)) >> 16;
}
// k-pos -> unit permutations (match packed h write layouts)
__device__ __forceinline__ int upos1(int p){ return 16*(p>>4) + 4*(p&3) + ((p>>2)&3); }
__device__ __forceinline__ int upos2(int p){ return 8*(p>>3) + 4*(p&1) + ((p&7)>>1); }

__device__ __forceinline__ float rcpf(float x){ return __builtin_amdgcn_rcpf(x); }
#if __has_builtin(__builtin_amdgcn_exp2f)
__device__ __forceinline__ float ex2(float x){ return __builtin_amdgcn_exp2f(x); }
#else
__device__ __forceinline__ float ex2(float x){
    float r; asm("v_exp_f32 %0, %1\n\ts_nop 0" : "=v"(r) : "v"(x)); return r;
}
#endif

// gates pre-scaled: i,f,o by -log2e ; g by +2log2e. cs = 2log2e*c carried.
__device__ __forceinline__ float actf(const f32x4 a, float& cs){
    float Ei = ex2(a[0]), Ef = ex2(a[1]), Eg = ex2(a[2]), Eo = ex2(a[3]);
    float si = rcpf(1.0f + Ei), sf = rcpf(1.0f + Ef);
    float rg = rcpf(1.0f + Eg), so = rcpf(1.0f + Eo);
    float gt2 = __builtin_fmaf(-4.0f * LOG2E, rg, 2.0f * LOG2E);   // 2log2e*tanh(g)
    cs = __builtin_fmaf(sf, cs, si * gt2);
    float Ec = ex2(cs);
    float tc = __builtin_fmaf(-2.0f, rcpf(1.0f + Ec), 1.0f);       // tanh(c)
    return so * tc;
}

__global__ __launch_bounds__(512, 2)
void lstm_ar_kernel(const float* __restrict__ x_in,
                    const float* __restrict__ dly_in,
                    const float* __restrict__ W_ih1, const float* __restrict__ W_hh1,
                    const float* __restrict__ b_ih1, const float* __restrict__ b_hh1,
                    const float* __restrict__ W_ih2, const float* __restrict__ W_hh2,
                    const float* __restrict__ b_ih2, const float* __restrict__ b_hh2,
                    const float* __restrict__ W_out, const float* __restrict__ b_out,
                    float* __restrict__ out)
{
    // h1 rows: upos1 order, 64 entries + pad, stride 72 us (144B).
    // h2 rows: upos2 order, 32 entries + pad, stride 40 us (80B).
    __shared__ __align__(16) us H1[2][16][72];
    __shared__ __align__(16) us H2[2][16][40];

    const int tid = threadIdx.x, w = tid >> 6, l = tid & 63;
    const int lb = l & 15, lq = l >> 4;
    const int bglob = blockIdx.x * 16 + lb;

    for (int i = tid; i < 2*16*72; i += 512) ((us*)H1)[i] = 0;
    for (int i = tid; i < 2*16*40; i += 512) ((us*)H2)[i] = 0;

    const int ty = lb & 3, du = lb >> 2;
    const float srow = (ty == 2) ? 2.0f * LOG2E : -LOG2E;
    const bool isA = (w < 4);
    const int  w2  = w & 3;

    // A role: 4 L1 tiles. B role: 2 L2 tiles (+ y on w4).
    short8 w1h[4][2], wxd[4];
    short8 w2h[2][2], whh[2], wbb[2];
    short8 wyh = {}, wyl = {};

    if (isA) {
        #pragma unroll
        for (int m = 0; m < 4; ++m) {
            const int G = ty * 64 + 16 * w + 4 * m + du;
            #pragma unroll
            for (int s = 0; s < 2; ++s)
                #pragma unroll
                for (int i = 0; i < 8; ++i) {
                    int p = 32*s + 8*lq + i;
                    float v = srow * W_hh1[G * 64 + upos1(p)];
                    w1h[m][s][i] = (short)rtne(v);          // single RTNE bf16
                }
            float q4 = 0.25f * srow;
            float wx = q4 * W_ih1[G*2+0], wd = q4 * W_ih1[G*2+1];
            float bb = q4 * (b_ih1[G] + b_hh1[G]);
            float wxh = hmask(wx), wdh = hmask(wd), bbh = hmask(bb);
            wxd[m] = (short8){ (short)bhi(wx), (short)bhi(wx), (short)bhi(wd),
                               (short)bhi(wd), (short)bhi(bb), (short)bhi(wx - wxh),
                               (short)bhi(wd - wdh), (short)bhi(bb - bbh) };
        }
    } else {
        #pragma unroll
        for (int j = 0; j < 2; ++j) {
            const int G2 = ty * 32 + 8 * w2 + 4 * j + du;
            #pragma unroll
            for (int s = 0; s < 2; ++s)
                #pragma unroll
                for (int i = 0; i < 8; ++i) {
                    int p = 32*s + 8*lq + i;
                    float v = srow * W_ih2[G2 * 64 + upos1(p)];   // h1 pos-order
                    w2h[j][s][i] = (short)rtne(v);
                }
            #pragma unroll
            for (int i = 0; i < 8; ++i) {
                float v = srow * W_hh2[G2 * 32 + upos2(8*lq + i)]; // h2 pos-order
                whh[j][i] = (short)rtne(v);
            }
            float bb = 0.25f * srow * (b_ih2[G2] + b_hh2[G2]);
            float bbh = hmask(bb);
            wbb[j] = (short8){ (short)bhi(bb), (short)bhi(bb - bbh), 0,0,0,0,0,0 };
        }
        if (w == 4) {
            #pragma unroll
            for (int i = 0; i < 8; ++i) {
                float v = (lb == 0) ? W_out[upos2(8*lq + i)] : 0.0f;
                float vh = hmask(v);
                wyh[i] = (short)bhi(v);
                wyl[i] = (short)bhi(v - vh);     // keep y exact (1 extra MFMA, wave4 only)
            }
        }
    }
    const float bout = b_out[0];
    const short8 bB = (short8){(short)0x3F80,(short)0x3F80,0,0,0,0,0,0};
    const f32x4  Z4 = {0.f,0.f,0.f,0.f};

    const float* xp = x_in   + bglob * T;
    const float* dp = dly_in + bglob * T;
    float*       op = out    + bglob * T;

    float c1[4] = {0.f,0.f,0.f,0.f};   // A: 4 units; B: [0..1] = c2
    float2 xc = {0,0}, dc = {0,0};
    if (isA) { xc = *(const float2*)xp; dc = *(const float2*)dp; }

    __syncthreads();

    auto STEP = [&](const int t, const int pw, const int pr,
                    const float xv, const float dv) {
        if (isA) {
            if (t < T) {
                const us* r1 = &H1[pr][lb][0];
                short8 hh0 = *(const short8*)(r1 + 8*lq);
                short8 hh1 = *(const short8*)(r1 + 32 + 8*lq);
                uu xu = __float_as_uint(xv), duu = __float_as_uint(dv);
                float xlo = xv - __uint_as_float(xu & 0xFFFF0000u);
                float dlo = dv - __uint_as_float(duu & 0xFFFF0000u);
                short8 bx;
                ((uu*)&bx)[0] = (xu >> 16)  | (__float_as_uint(xlo) & 0xFFFF0000u);
                ((uu*)&bx)[1] = (duu >> 16) | (__float_as_uint(dlo) & 0xFFFF0000u);
                ((uu*)&bx)[2] = 0x00003F80u | (xu & 0xFFFF0000u);
                ((uu*)&bx)[3] = (duu >> 16) | 0x3F800000u;

                // per tile: a0-chain (w k0, xd) + a1-chain (w k1)
                f32x4 a0[4], a1[4];
                #pragma unroll
                for (int m = 0; m < 4; ++m) a0[m] = MFMA16(w1h[m][0], hh0, Z4);
                #pragma unroll
                for (int m = 0; m < 4; ++m) a1[m] = MFMA16(w1h[m][1], hh1, Z4);
                #pragma unroll
                for (int m = 0; m < 4; ++m) a0[m] = MFMA16(wxd[m], bx, a0[m]);

                float hv[4];
                #pragma unroll
                for (int m = 0; m < 4; ++m) {
                    f32x4 g = { a0[m][0]+a1[m][0], a0[m][1]+a1[m][1],
                                a0[m][2]+a1[m][2], a0[m][3]+a1[m][3] };
                    hv[m] = actf(g, c1[m]);
                }
                uu P0 = rtne(hv[0]) | (rtne(hv[1]) << 16);
                uu P1 = rtne(hv[2]) | (rtne(hv[3]) << 16);
                *(uint2*)&H1[pw][lb][16*w + 4*lq] = (uint2){P0, P1};
            }
        } else {
            short8 g0 = {};
            if (t >= 1) {
                const us* r2 = &H2[pw][lb][0];       // h2(t-2)
                g0 = *(const short8*)(r2 + 8*lq);
            }
            // y(t-2) on wave 4
            if (w == 4 && t >= 2) {
                f32x4 yA = MFMA16(wyh, g0, Z4);
                f32x4 yB = MFMA16(wyl, g0, Z4);
                if (lq == 0) op[t-2] = yA[0] + yB[0] + bout;
            }
            // L2: h2(t-1) from h1(t-1) [slot pr] and h2(t-2) [slot pw]
            if (t >= 1 && t <= T) {
                const us* r1 = &H1[pr][lb][0];
                short8 hh0 = *(const short8*)(r1 + 8*lq);
                short8 hh1 = *(const short8*)(r1 + 32 + 8*lq);

                // per tile: qA (ih k0, bias), qB (ih k1), qC (hh)
                f32x4 qA[2], qB[2], qC[2];
                #pragma unroll
                for (int j = 0; j < 2; ++j) {
                    qA[j] = MFMA16(w2h[j][0], hh0, Z4);
                    qB[j] = MFMA16(w2h[j][1], hh1, Z4);
                    qC[j] = MFMA16(whh[j],    g0,  Z4);
                }
                #pragma unroll
                for (int j = 0; j < 2; ++j)
                    qA[j] = MFMA16(wbb[j], bB, qA[j]);

                float h2v[2];
                #pragma unroll
                for (int j = 0; j < 2; ++j) {
                    f32x4 g = { qA[j][0]+qB[j][0]+qC[j][0], qA[j][1]+qB[j][1]+qC[j][1],
                                qA[j][2]+qB[j][2]+qC[j][2], qA[j][3]+qB[j][3]+qC[j][3] };
                    h2v[j] = actf(g, c1[j]);
                }
                uu ph = rtne(h2v[0]) | (rtne(h2v[1]) << 16);
                *(uu*)&H2[pr][lb][8*w2 + 2*lq] = ph;
            }
        }
        BARRIER();
    };

    #pragma unroll 1
    for (int tt = 0; tt <= 512; ++tt) {
        float2 xn = xc, dn = dc;
        if (isA) {
            const int wn = (tt < 511) ? tt + 1 : 511;
            xn = *(const float2*)(xp + 2*wn);
            dn = *(const float2*)(dp + 2*wn);
        }
        STEP(2*tt,     0, 1, xc.x, dc.x);
        STEP(2*tt + 1, 1, 0, xc.y, dc.y);
        xc = xn; dc = dn;
    }
}

extern "C" void kernel_launch(void* const* d_in, const int* in_sizes, int n_in,
                              void* d_out, int out_size, void* d_ws, size_t ws_size,
                              hipStream_t stream) {
    lstm_ar_kernel<<<dim3(64), dim3(512), 0, stream>>>(
        (const float*)d_in[0],  (const float*)d_in[1],
        (const float*)d_in[2],  (const float*)d_in[3],
        (const float*)d_in[4],  (const float*)d_in[5],
        (const float*)d_in[6],  (const float*)d_in[7],
        (const float*)d_in[8],  (const float*)d_in[9],
        (const float*)d_in[10], (const float*)d_in[11],
        (float*)d_out);
}

// Round 13
// 597.040 us; speedup vs baseline: 1.4537x; 1.0727x over previous
//
#include <hip/hip_runtime.h>

// LSTMAutoRegressive: B=1024, T=1024, H1=64, H2=32, n_in=n_out=1.
// v12 = v11 + micro-cuts under the additive per-SIMD issue law (R5-R11:
// step = MFMA-issue + VALU-issue, no overlap):
//  (1) A: single 3-deep chain per tile (wk0 -> xd -> wk1), no merge adds
//  (2) B: qA 3-chain (ihk0 -> bias -> ihk1) + qC(hh), single merge
//  (3) h packing via v_cvt_pk_bf16_f32 (2 instrs replace ~14 bit-twiddles)
// 64 wgs x 512 threads. Role-split: w0-3 L1 (4 tiles), w4-7 L2 (2 tiles)+y.
// Weights & h single RTNE bf16; exp2-folded weights; xd folded as MFMA
// k-step; 1 lgkm-only barrier per step.

using short8 = __attribute__((ext_vector_type(8))) short;
using f32x4  = __attribute__((ext_vector_type(4))) float;
typedef unsigned short us;
typedef unsigned int   uu;

#define MFMA16(A,B,C) __builtin_amdgcn_mfma_f32_16x16x32_bf16((A),(B),(C),0,0,0)
#define BARRIER() asm volatile("s_waitcnt lgkmcnt(0)\n\ts_barrier" ::: "memory")

constexpr int   T     = 1024;
constexpr float LOG2E = 1.44269504088896f;

__device__ __forceinline__ us    bhi(float f){ return (us)(__float_as_uint(f) >> 16); }
__device__ __forceinline__ float hmask(float f){ return __uint_as_float(__float_as_uint(f) & 0xFFFF0000u); }
__device__ __forceinline__ uu rtne(float f){
    uu u = __float_as_uint(f);
    return (u + 0x7FFFu + ((u >> 16) & 1u)) >> 16;
}
// packed RNE bf16 pair: [15:0]=cvt(lo), [31:16]=cvt(hi)
__device__ __forceinline__ uu pk_bf16(float lo, float hi){
    uu r;
    asm("v_cvt_pk_bf16_f32 %0, %1, %2" : "=v"(r) : "v"(lo), "v"(hi));
    return r;
}
// k-pos -> unit permutations (match packed h write layouts)
__device__ __forceinline__ int upos1(int p){ return 16*(p>>4) + 4*(p&3) + ((p>>2)&3); }
__device__ __forceinline__ int upos2(int p){ return 8*(p>>3) + 4*(p&1) + ((p&7)>>1); }

__device__ __forceinline__ float rcpf(float x){ return __builtin_amdgcn_rcpf(x); }
#if __has_builtin(__builtin_amdgcn_exp2f)
__device__ __forceinline__ float ex2(float x){ return __builtin_amdgcn_exp2f(x); }
#else
__device__ __forceinline__ float ex2(float x){
    float r; asm("v_exp_f32 %0, %1\n\ts_nop 0" : "=v"(r) : "v"(x)); return r;
}
#endif

// gates pre-scaled: i,f,o by -log2e ; g by +2log2e. cs = 2log2e*c carried.
__device__ __forceinline__ float actf(const f32x4 a, float& cs){
    float Ei = ex2(a[0]), Ef = ex2(a[1]), Eg = ex2(a[2]), Eo = ex2(a[3]);
    float si = rcpf(1.0f + Ei), sf = rcpf(1.0f + Ef);
    float rg = rcpf(1.0f + Eg), so = rcpf(1.0f + Eo);
    float gt2 = __builtin_fmaf(-4.0f * LOG2E, rg, 2.0f * LOG2E);   // 2log2e*tanh(g)
    cs = __builtin_fmaf(sf, cs, si * gt2);
    float Ec = ex2(cs);
    float tc = __builtin_fmaf(-2.0f, rcpf(1.0f + Ec), 1.0f);       // tanh(c)
    return so * tc;
}

__global__ __launch_bounds__(512, 2)
void lstm_ar_kernel(const float* __restrict__ x_in,
                    const float* __restrict__ dly_in,
                    const float* __restrict__ W_ih1, const float* __restrict__ W_hh1,
                    const float* __restrict__ b_ih1, const float* __restrict__ b_hh1,
                    const float* __restrict__ W_ih2, const float* __restrict__ W_hh2,
                    const float* __restrict__ b_ih2, const float* __restrict__ b_hh2,
                    const float* __restrict__ W_out, const float* __restrict__ b_out,
                    float* __restrict__ out)
{
    // h1 rows: upos1 order, 64 entries + pad, stride 72 us (144B).
    // h2 rows: upos2 order, 32 entries + pad, stride 40 us (80B).
    __shared__ __align__(16) us H1[2][16][72];
    __shared__ __align__(16) us H2[2][16][40];

    const int tid = threadIdx.x, w = tid >> 6, l = tid & 63;
    const int lb = l & 15, lq = l >> 4;
    const int bglob = blockIdx.x * 16 + lb;

    for (int i = tid; i < 2*16*72; i += 512) ((us*)H1)[i] = 0;
    for (int i = tid; i < 2*16*40; i += 512) ((us*)H2)[i] = 0;

    const int ty = lb & 3, du = lb >> 2;
    const float srow = (ty == 2) ? 2.0f * LOG2E : -LOG2E;
    const bool isA = (w < 4);
    const int  w2  = w & 3;

    // A role: 4 L1 tiles. B role: 2 L2 tiles (+ y on w4).
    short8 w1h[4][2], wxd[4];
    short8 w2h[2][2], whh[2], wbb[2];
    short8 wyh = {}, wyl = {};

    if (isA) {
        #pragma unroll
        for (int m = 0; m < 4; ++m) {
            const int G = ty * 64 + 16 * w + 4 * m + du;
            #pragma unroll
            for (int s = 0; s < 2; ++s)
                #pragma unroll
                for (int i = 0; i < 8; ++i) {
                    int p = 32*s + 8*lq + i;
                    float v = srow * W_hh1[G * 64 + upos1(p)];
                    w1h[m][s][i] = (short)rtne(v);          // single RTNE bf16
                }
            float q4 = 0.25f * srow;
            float wx = q4 * W_ih1[G*2+0], wd = q4 * W_ih1[G*2+1];
            float bb = q4 * (b_ih1[G] + b_hh1[G]);
            float wxh = hmask(wx), wdh = hmask(wd), bbh = hmask(bb);
            wxd[m] = (short8){ (short)bhi(wx), (short)bhi(wx), (short)bhi(wd),
                               (short)bhi(wd), (short)bhi(bb), (short)bhi(wx - wxh),
                               (short)bhi(wd - wdh), (short)bhi(bb - bbh) };
        }
    } else {
        #pragma unroll
        for (int j = 0; j < 2; ++j) {
            const int G2 = ty * 32 + 8 * w2 + 4 * j + du;
            #pragma unroll
            for (int s = 0; s < 2; ++s)
                #pragma unroll
                for (int i = 0; i < 8; ++i) {
                    int p = 32*s + 8*lq + i;
                    float v = srow * W_ih2[G2 * 64 + upos1(p)];   // h1 pos-order
                    w2h[j][s][i] = (short)rtne(v);
                }
            #pragma unroll
            for (int i = 0; i < 8; ++i) {
                float v = srow * W_hh2[G2 * 32 + upos2(8*lq + i)]; // h2 pos-order
                whh[j][i] = (short)rtne(v);
            }
            float bb = 0.25f * srow * (b_ih2[G2] + b_hh2[G2]);
            float bbh = hmask(bb);
            wbb[j] = (short8){ (short)bhi(bb), (short)bhi(bb - bbh), 0,0,0,0,0,0 };
        }
        if (w == 4) {
            #pragma unroll
            for (int i = 0; i < 8; ++i) {
                float v = (lb == 0) ? W_out[upos2(8*lq + i)] : 0.0f;
                float vh = hmask(v);
                wyh[i] = (short)bhi(v);
                wyl[i] = (short)bhi(v - vh);     // y kept exact (wave4 only)
            }
        }
    }
    const float bout = b_out[0];
    const short8 bB = (short8){(short)0x3F80,(short)0x3F80,0,0,0,0,0,0};
    const f32x4  Z4 = {0.f,0.f,0.f,0.f};

    const float* xp = x_in   + bglob * T;
    const float* dp = dly_in + bglob * T;
    float*       op = out    + bglob * T;

    float c1[4] = {0.f,0.f,0.f,0.f};   // A: 4 units; B: [0..1] = c2
    float2 xc = {0,0}, dc = {0,0};
    if (isA) { xc = *(const float2*)xp; dc = *(const float2*)dp; }

    __syncthreads();

    auto STEP = [&](const int t, const int pw, const int pr,
                    const float xv, const float dv) {
        if (isA) {
            if (t < T) {
                const us* r1 = &H1[pr][lb][0];
                short8 hh0 = *(const short8*)(r1 + 8*lq);
                short8 hh1 = *(const short8*)(r1 + 32 + 8*lq);
                uu xu = __float_as_uint(xv), duu = __float_as_uint(dv);
                float xlo = xv - __uint_as_float(xu & 0xFFFF0000u);
                float dlo = dv - __uint_as_float(duu & 0xFFFF0000u);
                short8 bx;
                ((uu*)&bx)[0] = (xu >> 16)  | (__float_as_uint(xlo) & 0xFFFF0000u);
                ((uu*)&bx)[1] = (duu >> 16) | (__float_as_uint(dlo) & 0xFFFF0000u);
                ((uu*)&bx)[2] = 0x00003F80u | (xu & 0xFFFF0000u);
                ((uu*)&bx)[3] = (duu >> 16) | 0x3F800000u;

                // single 3-deep chain per tile: wk0 -> xd -> wk1 (4 interleaved)
                f32x4 a[4];
                #pragma unroll
                for (int m = 0; m < 4; ++m) a[m] = MFMA16(w1h[m][0], hh0, Z4);
                #pragma unroll
                for (int m = 0; m < 4; ++m) a[m] = MFMA16(wxd[m],    bx,  a[m]);
                #pragma unroll
                for (int m = 0; m < 4; ++m) a[m] = MFMA16(w1h[m][1], hh1, a[m]);

                float hv[4];
                #pragma unroll
                for (int m = 0; m < 4; ++m) hv[m] = actf(a[m], c1[m]);

                uint2 P = { pk_bf16(hv[0], hv[1]), pk_bf16(hv[2], hv[3]) };
                *(uint2*)&H1[pw][lb][16*w + 4*lq] = P;
            }
        } else {
            short8 g0 = {};
            if (t >= 1) {
                const us* r2 = &H2[pw][lb][0];       // h2(t-2)
                g0 = *(const short8*)(r2 + 8*lq);
            }
            // y(t-2) on wave 4
            if (w == 4 && t >= 2) {
                f32x4 yA = MFMA16(wyh, g0, Z4);
                f32x4 yB = MFMA16(wyl, g0, Z4);
                if (lq == 0) op[t-2] = yA[0] + yB[0] + bout;
            }
            // L2: h2(t-1) from h1(t-1) [slot pr] and h2(t-2) [slot pw]
            if (t >= 1 && t <= T) {
                const us* r1 = &H1[pr][lb][0];
                short8 hh0 = *(const short8*)(r1 + 8*lq);
                short8 hh1 = *(const short8*)(r1 + 32 + 8*lq);

                // per tile: qA 3-chain (ihk0 -> bias -> ihk1) + qC (hh); 1 merge
                f32x4 qA[2], qC[2];
                #pragma unroll
                for (int j = 0; j < 2; ++j) { qA[j] = MFMA16(w2h[j][0], hh0, Z4);
                                              qC[j] = MFMA16(whh[j],    g0,  Z4); }
                #pragma unroll
                for (int j = 0; j < 2; ++j)   qA[j] = MFMA16(wbb[j],    bB,  qA[j]);
                #pragma unroll
                for (int j = 0; j < 2; ++j)   qA[j] = MFMA16(w2h[j][1], hh1, qA[j]);

                float h2v[2];
                #pragma unroll
                for (int j = 0; j < 2; ++j) {
                    f32x4 g = qA[j] + qC[j];
                    h2v[j] = actf(g, c1[j]);
                }
                *(uu*)&H2[pr][lb][8*w2 + 2*lq] = pk_bf16(h2v[0], h2v[1]);
            }
        }
        BARRIER();
    };

    #pragma unroll 1
    for (int tt = 0; tt <= 512; ++tt) {
        float2 xn = xc, dn = dc;
        if (isA) {
            const int wn = (tt < 511) ? tt + 1 : 511;
            xn = *(const float2*)(xp + 2*wn);
            dn = *(const float2*)(dp + 2*wn);
        }
        STEP(2*tt,     0, 1, xc.x, dc.x);
        STEP(2*tt + 1, 1, 0, xc.y, dc.y);
        xc = xn; dc = dn;
    }
}

extern "C" void kernel_launch(void* const* d_in, const int* in_sizes, int n_in,
                              void* d_out, int out_size, void* d_ws, size_t ws_size,
                              hipStream_t stream) {
    lstm_ar_kernel<<<dim3(64), dim3(512), 0, stream>>>(
        (const float*)d_in[0],  (const float*)d_in[1],
        (const float*)d_in[2],  (const float*)d_in[3],
        (const float*)d_in[4],  (const float*)d_in[5],
        (const float*)d_in[6],  (const float*)d_in[7],
        (const float*)d_in[8],  (const float*)d_in[9],
        (const float*)d_in[10], (const float*)d_in[11],
        (float*)d_out);
}